// Round 11
// baseline (2607.282 us; speedup 1.0000x reference)
//
#include <hip/hip_runtime.h>
#include <stdint.h>
#include <stddef.h>

#define MSTEPS 128
#define NB 1024
#define ED 512
#define GD 1536
#define VS 32000

// GRU decomposition: 64 row-blocks x 16 rows, 8 col-WGs x 64 cols.
// 512 WGs x 256 threads (4 waves) = 2 WGs/CU for latency overlap.
// W_hh in VGPRs (192/lane, r3-proven at 4-wave WG). 2-buffer ping-pong
// in L3. Exchange: relaxed agent (sc1) loads/stores; per-producer flags,
// release-arrive + RELAXED spin (acquire-in-spin = L2-inv storm, r7).
// Each wave waits only on its 2 producers and loads those slices (skew
// overlap). s=0 skips the state load (h0=0) -> written-before-read.
#define RB 16
#define CB 64
#define NGR 64   // row-block groups
#define NSH 8    // sharers (col-WGs) per group
#define GIST 200 // gi LDS row stride (elems): 3*64 data + 8 pad
#define STST 72  // stl LDS row stride (elems): 64 data + 8 pad

typedef __attribute__((ext_vector_type(4))) float f32x4;
typedef __attribute__((ext_vector_type(8))) short s16x8;
typedef __attribute__((ext_vector_type(4))) short s16x4;
typedef __attribute__((ext_vector_type(8))) unsigned short u16x8;

__device__ __forceinline__ unsigned short f2bf(float f) {
  unsigned x = __builtin_bit_cast(unsigned, f);
  x = x + 0x7fffu + ((x >> 16) & 1u);
  return (unsigned short)(x >> 16);
}
__device__ __forceinline__ float bf2f(unsigned short u) {
  return __builtin_bit_cast(float, ((unsigned)u) << 16);
}
__device__ __forceinline__ float sigm(float x) { return 1.0f / (1.0f + __expf(-x)); }
__device__ __forceinline__ float tanh_(float x) {
  x = fminf(15.0f, fmaxf(-15.0f, x));
  float e = __expf(-2.0f * x);
  return (1.0f - e) / (1.0f + e);
}

// ---------------- Kernel 1: projected vocab table (r2-proven) ----------------
__global__ __launch_bounds__(256) void table_kernel(
    const float* __restrict__ emb, const float* __restrict__ Wih,
    const float* __restrict__ bih, unsigned short* __restrict__ tab)
{
  __shared__ short Al[128 * 64];
  __shared__ short Bl[128 * 64];
  const int tid = threadIdx.x;
  const int lane = tid & 63;
  const int l15 = lane & 15, l4 = lane >> 4;
  const int wv = tid >> 6;
  const int rh = wv & 1, ch = wv >> 1;
  const int row0 = blockIdx.x * 128;
  const int col0 = blockIdx.y * 128;

  f32x4 acc[4][4];
  #pragma unroll
  for (int m = 0; m < 4; m++)
    #pragma unroll
    for (int n = 0; n < 4; n++) acc[m][n] = (f32x4){0.f, 0.f, 0.f, 0.f};

  for (int ko = 0; ko < ED; ko += 64) {
    #pragma unroll
    for (int i = 0; i < 8; i++) {
      int idx = tid + i * 256;
      int r = idx >> 4, c4 = idx & 15;
      int ba = (r * 128 + c4 * 8) ^ ((r & 7) << 4);
      f32x4 va = *(const f32x4*)(emb + (size_t)(row0 + r) * ED + ko + c4 * 4);
      s16x4 pa;
      pa[0] = (short)f2bf(va[0]); pa[1] = (short)f2bf(va[1]);
      pa[2] = (short)f2bf(va[2]); pa[3] = (short)f2bf(va[3]);
      *(s16x4*)((char*)Al + ba) = pa;
      f32x4 vb = *(const f32x4*)(Wih + (size_t)(col0 + r) * ED + ko + c4 * 4);
      s16x4 pb;
      pb[0] = (short)f2bf(vb[0]); pb[1] = (short)f2bf(vb[1]);
      pb[2] = (short)f2bf(vb[2]); pb[3] = (short)f2bf(vb[3]);
      *(s16x4*)((char*)Bl + ba) = pb;
    }
    __syncthreads();
    #pragma unroll
    for (int kk = 0; kk < 2; kk++) {
      s16x8 af[4], bfv[4];
      #pragma unroll
      for (int m = 0; m < 4; m++) {
        int row = rh * 64 + m * 16 + l15;
        int ad = (row * 128 + kk * 64 + l4 * 16) ^ ((row & 7) << 4);
        af[m] = *(const s16x8*)((char*)Al + ad);
      }
      #pragma unroll
      for (int n = 0; n < 4; n++) {
        int col = ch * 64 + n * 16 + l15;
        int ad = (col * 128 + kk * 64 + l4 * 16) ^ ((col & 7) << 4);
        bfv[n] = *(const s16x8*)((char*)Bl + ad);
      }
      #pragma unroll
      for (int m = 0; m < 4; m++)
        #pragma unroll
        for (int n = 0; n < 4; n++)
          acc[m][n] = __builtin_amdgcn_mfma_f32_16x16x32_bf16(af[m], bfv[n], acc[m][n], 0, 0, 0);
    }
    __syncthreads();
  }

  float bias_n[4];
  #pragma unroll
  for (int n = 0; n < 4; n++) bias_n[n] = bih[col0 + ch * 64 + n * 16 + l15];
  #pragma unroll
  for (int m = 0; m < 4; m++)
    #pragma unroll
    for (int n = 0; n < 4; n++) {
      int colg = col0 + ch * 64 + n * 16 + l15;
      #pragma unroll
      for (int j = 0; j < 4; j++) {
        int rowg = row0 + rh * 64 + m * 16 + l4 * 4 + j;
        tab[(size_t)rowg * GD + colg] = f2bf(acc[m][n][j] + bias_n[n]);
      }
    }
}

// ---------------- Kernel 2: persistent GRU scan ----------------
__global__ __launch_bounds__(256, 2) void gru_kernel(
    const int* __restrict__ utt, const float* __restrict__ Whh,
    const float* __restrict__ bhh, const unsigned short* __restrict__ tab,
    unsigned short* st0, unsigned short* st1,
    unsigned* cnt, const int* __restrict__ termp,
    float* __restrict__ out)
{
  __shared__ __align__(16) char sls[RB * 1024];            // state tile 16KB (512 cols)
  __shared__ __align__(16) unsigned short gil[RB * GIST];  // 6.25KB
  __shared__ __align__(16) unsigned short stl[RB * STST];  // 2.25KB
  __shared__ int abl;

  const int tid = threadIdx.x;
  const int lane = tid & 63;
  const int l15 = lane & 15, l4 = lane >> 4;
  const int wv = tid >> 6;                 // wave 0..3
  const int bid = blockIdx.x;
  const int rblk = bid & (NGR - 1);        // 0..63
  const int cblk = bid >> 6;               // 0..7
  const int r0 = rblk * RB, c0 = cblk * CB;
  const int wc = wv * 16 + l15;            // col within WG tile, 0..63
  const int termid = termp[0];

  unsigned* fg = cnt + rblk * 16;          // 8 flags per group, one 64B line
  int* abort_g = (int*)(cnt + 2048);

  if (tid == 0) abl = 0;

  // ---- W_hh fragments -> VGPRs (192/lane, r3-proven) ----
  s16x8 bfr[3][16];
  #pragma unroll
  for (int g = 0; g < 3; g++)
    #pragma unroll
    for (int kk = 0; kk < 16; kk++) {
      const float* src = Whh + (size_t)(g * ED + c0 + wc) * ED + kk * 32 + l4 * 8;
      f32x4 v0 = *(const f32x4*)(src);
      f32x4 v1 = *(const f32x4*)(src + 4);
      s16x8 p;
      p[0] = (short)f2bf(v0[0]); p[1] = (short)f2bf(v0[1]);
      p[2] = (short)f2bf(v0[2]); p[3] = (short)f2bf(v0[3]);
      p[4] = (short)f2bf(v1[0]); p[5] = (short)f2bf(v1[1]);
      p[6] = (short)f2bf(v1[2]); p[7] = (short)f2bf(v1[3]);
      bfr[g][kk] = p;
    }

  float bh[3];
  #pragma unroll
  for (int g = 0; g < 3; g++) bh[g] = bhh[g * ED + c0 + wc];

  float ms[4] = {0.f, 0.f, 0.f, 0.f};     // master state rows l4*4+j, col wc
  unsigned am = 0xFu;                      // alive bits, 4 owned rows

  // gather: 16 rows x 24 units(16B) = 384 units/step; tid (+256+tid if tid<128)
  int grow_[2], goff_[2];
  const unsigned short* gtb_[2];
  #pragma unroll
  for (int k = 0; k < 2; k++) {
    int u = tid + k * 256;                 // k=1 valid only for tid<128
    int uu = (k == 1 && tid >= 128) ? 0 : u;
    grow_[k] = uu / 24;
    int seg = uu % 24;
    int gate = seg >> 3, cs = seg & 7;
    goff_[k] = gate * 64 + cs * 8;
    gtb_[k] = tab + (size_t)gate * ED + c0 + cs * 8;   // + tok*GD at use
  }
  const bool has2 = (tid < 128);

  // prefetch step-0 gather + tokens
  u16x8 pg[2];
  int ptoks[4];
  {
    int tok0 = utt[r0 + grow_[0]];
    pg[0] = *(const u16x8*)(gtb_[0] + (size_t)tok0 * GD);
    if (has2) {
      int tok1 = utt[r0 + grow_[1]];
      pg[1] = *(const u16x8*)(gtb_[1] + (size_t)tok1 * GD);
    }
    #pragma unroll
    for (int j = 0; j < 4; j++) ptoks[j] = utt[r0 + l4 * 4 + j];
  }

  __syncthreads();

  for (int s = 0; s < MSTEPS; s++) {
    const unsigned short* rdb = (s & 1) ? st1 : st0;
    unsigned short* wrb = (s & 1) ? st0 : st1;

    // 1) park prefetched gi into LDS; snapshot tokens
    *(u16x8*)(gil + grow_[0] * GIST + goff_[0]) = pg[0];
    if (has2) *(u16x8*)(gil + grow_[1] * GIST + goff_[1]) = pg[1];
    int tk[4];
    #pragma unroll
    for (int j = 0; j < 4; j++) tk[j] = ptoks[j];

    // 2) acquire state tile slice-by-slice: wave wv handles producers
    //    2wv and 2wv+1. Wait flag (RELAXED spin), then 8B agent loads.
    if (s > 0) {
      const unsigned long long* rdb64 = (const unsigned long long*)rdb;
      #pragma unroll
      for (int p2 = 0; p2 < 2; p2++) {
        int p = 2 * wv + p2;
        const unsigned tgt = (unsigned)s;
        unsigned long long t0 = __builtin_amdgcn_s_memrealtime();
        int pc = 0;
        while (__hip_atomic_load(fg + p, __ATOMIC_RELAXED, __HIP_MEMORY_SCOPE_AGENT) < tgt) {
          if (((++pc) & 63) == 0) {
            if (__hip_atomic_load(abort_g, __ATOMIC_RELAXED, __HIP_MEMORY_SCOPE_AGENT)) { abl = 1; break; }
            if (__builtin_amdgcn_s_memrealtime() - t0 > 20000000ULL) {
              __hip_atomic_store(abort_g, 1, __ATOMIC_RELAXED, __HIP_MEMORY_SCOPE_AGENT);
              abl = 1; break;
            }
          }
        }
        asm volatile("" ::: "memory");     // loads below stay below the spin
        // slice p: 16 rows x 16 u64 (64 cols); 4 u64 per lane
        #pragma unroll
        for (int i = 0; i < 4; i++) {
          int idx = i * 64 + lane;         // 0..255
          int row = idx >> 4, c8 = idx & 15;
          unsigned long long v = __hip_atomic_load(
              rdb64 + (size_t)(r0 + row) * 128 + p * 16 + c8,
              __ATOMIC_RELAXED, __HIP_MEMORY_SCOPE_AGENT);
          int o = row * 1024 + p * 128 + c8 * 8;
          *(unsigned long long*)(sls + (o ^ ((row & 7) << 4))) = v;
        }
      }
    }
    __syncthreads();

    // 3) prefetch next step's gather + tokens (hidden under MFMA)
    if (s + 1 < MSTEPS) {
      int tok0 = utt[(s + 1) * NB + r0 + grow_[0]];
      pg[0] = *(const u16x8*)(gtb_[0] + (size_t)tok0 * GD);
      if (has2) {
        int tok1 = utt[(s + 1) * NB + r0 + grow_[1]];
        pg[1] = *(const u16x8*)(gtb_[1] + (size_t)tok1 * GD);
      }
      #pragma unroll
      for (int j = 0; j < 4; j++) ptoks[j] = utt[(s + 1) * NB + r0 + l4 * 4 + j];
    }

    // 4) gh = state @ Whh^T  (A from LDS, B from regs); s=0: gh=0 exactly
    f32x4 acc[3];
    #pragma unroll
    for (int g = 0; g < 3; g++) acc[g] = (f32x4){0.f, 0.f, 0.f, 0.f};
    if (s > 0) {
      #pragma unroll
      for (int kk = 0; kk < 16; kk++) {
        int ad = (l15 * 1024 + kk * 64 + l4 * 16) ^ ((l15 & 7) << 4);
        s16x8 av = *(const s16x8*)(sls + ad);
        #pragma unroll
        for (int g = 0; g < 3; g++)
          acc[g] = __builtin_amdgcn_mfma_f32_16x16x32_bf16(av, bfr[g][kk], acc[g], 0, 0, 0);
      }
    }

    // 5) epilogue: gates + blend (f32 master state in regs)
    #pragma unroll
    for (int j = 0; j < 4; j++) {
      int row = l4 * 4 + j;
      float hr = acc[0][j] + bh[0];
      float hz = acc[1][j] + bh[1];
      float hn = acc[2][j] + bh[2];
      float ir = bf2f(gil[row * GIST + 0 * 64 + wc]);
      float iz = bf2f(gil[row * GIST + 1 * 64 + wc]);
      float in_ = bf2f(gil[row * GIST + 2 * 64 + wc]);
      float r = sigm(ir + hr);
      float z = sigm(iz + hz);
      float nn = tanh_(in_ + r * hn);
      float old = ms[j];
      float nu = (1.0f - z) * nn + z * old;
      float res = ((am >> j) & 1u) ? nu : old;
      ms[j] = res;
      stl[row * STST + wc] = f2bf(res);
      if (tk[j] == termid) am &= ~(1u << j);
    }
    __syncthreads();

    // 6) cooperative agent-scope store of new state slice (2KB/WG)
    {
      int srow = tid >> 4, seg = tid & 15;
      unsigned long long v = *(const unsigned long long*)(stl + srow * STST + seg * 4);
      unsigned long long* dst =
          (unsigned long long*)(wrb + (size_t)(r0 + srow) * ED + c0 + seg * 4);
      __hip_atomic_store(dst, v, __ATOMIC_RELAXED, __HIP_MEMORY_SCOPE_AGENT);
    }

    // 7) arrive: drain stores, barrier, release our flag
    asm volatile("s_waitcnt vmcnt(0)" ::: "memory");
    __syncthreads();
    if (tid == 0)
      __hip_atomic_store(fg + cblk, (unsigned)(s + 1), __ATOMIC_RELEASE, __HIP_MEMORY_SCOPE_AGENT);
    if (abl) break;
  }

  // final f32 state -> d_out
  #pragma unroll
  for (int j = 0; j < 4; j++) {
    int n = r0 + l4 * 4 + j;
    out[(size_t)n * ED + c0 + wc] = ms[j];
  }
}

__global__ void fail_kernel(float* out) {
  if (threadIdx.x == 0 && blockIdx.x == 0) out[0] = -54321.0f;
}

extern "C" void kernel_launch(void* const* d_in, const int* in_sizes, int n_in,
                              void* d_out, int out_size, void* d_ws, size_t ws_size,
                              hipStream_t stream) {
  const int* utt = (const int*)d_in[0];
  const float* emb = (const float*)d_in[1];
  const float* Wih = (const float*)d_in[2];
  const float* Whh = (const float*)d_in[3];
  const float* bih = (const float*)d_in[4];
  const float* bhh = (const float*)d_in[5];
  const int* term = (const int*)d_in[6];
  float* out = (float*)d_out;
  char* ws = (char*)d_ws;

  const size_t tab_b = (size_t)VS * GD * 2;                 // 98,304,000
  const size_t st_b = (size_t)NB * ED * 2;                  // 1,048,576
  const size_t off_st0 = tab_b;
  const size_t off_st1 = off_st0 + st_b;
  const size_t off_cnt = off_st1 + st_b;
  const size_t need = off_cnt + 12288;

  if (ws_size < need) {  // sentinel: visible failure instead of OOB
    fail_kernel<<<1, 64, 0, stream>>>(out);
    return;
  }

  unsigned short* tab = (unsigned short*)(ws);
  unsigned short* st0 = (unsigned short*)(ws + off_st0);
  unsigned short* st1 = (unsigned short*)(ws + off_st1);
  unsigned* cnt = (unsigned*)(ws + off_cnt);

  // flags + abort zeroed every launch (recorded in the graph, so every
  // replay re-zeroes). state buffers are written-before-read within each
  // call (s=0 skips the load), so no state memset is needed.
  (void)hipMemsetAsync(cnt, 0, 12288, stream);

  table_kernel<<<dim3(250, 12), 256, 0, stream>>>(emb, Wih, bih, tab);
  gru_kernel<<<512, 256, 0, stream>>>(utt, Whh, bhh, tab, st0, st1,
                                      cnt, term, out);
}